// Round 13
// baseline (805.648 us; speedup 1.0000x reference)
//
#include <hip/hip_runtime.h>
#include <hip/hip_bf16.h>
#include <hip/hip_cooperative_groups.h>

namespace cg = cooperative_groups;

// Problem constants
#define NLAYERS 2
#define DMODEL 1024
#define DINNER 2048
#define DSTATE 16
#define DCONV 4
#define DTRANK 64
#define BATCH 2
#define SEQ 1024
#define TOK (BATCH * SEQ)   // 2048 tokens

#define NCHUNK 32
#define CLEN (SEQ / NCHUNK)  // 32
#define KSX 16               // x_proj K-split
#define KSO 4                // out_proj K-split

typedef short bf16x8 __attribute__((ext_vector_type(8)));
typedef float f32x4 __attribute__((ext_vector_type(4)));
typedef unsigned short ushort8 __attribute__((ext_vector_type(8)));

__device__ __forceinline__ float softplusf(float x) {
    return (x > 20.f) ? x : log1pf(__expf(x));
}
__device__ __forceinline__ float siluf(float x) {
    return x / (1.f + __expf(-x));
}
__device__ __forceinline__ unsigned short f2bf(float f) {
    union { float f; unsigned int u; } v; v.f = f;
    const unsigned int r = (v.u + 0x7FFFu + ((v.u >> 16) & 1u)) >> 16;
    return (unsigned short)r;
}
__device__ __forceinline__ float bf2f(unsigned short s) {
    union { unsigned int u; float f; } v; v.u = ((unsigned int)s) << 16;
    return v.f;
}

// LDS swizzle (16-B granules, rows of 32 bf16 = 4 granules, involution):
// physical granule = (row>>1)*8 + ((((row&1)<<2)|kq) ^ ((row>>1)&7))
__device__ __forceinline__ int swz_granule(int row, int kq) {
    return (row >> 1) * 8 + ((((row & 1) << 2) | kq) ^ ((row >> 1) & 7));
}

// ---------------------------------------------------------------------------
// fp32 -> bf16, 8 elems/thread (helper)
// ---------------------------------------------------------------------------
__device__ __forceinline__ void cvt8(const float* __restrict__ in,
                                     unsigned short* __restrict__ out, int i) {
    const float4 a = reinterpret_cast<const float4*>(in)[i * 2 + 0];
    const float4 b = reinterpret_cast<const float4*>(in)[i * 2 + 1];
    ushort4 o0, o1;
    o0.x = f2bf(a.x); o0.y = f2bf(a.y); o0.z = f2bf(a.z); o0.w = f2bf(a.w);
    o1.x = f2bf(b.x); o1.y = f2bf(b.y); o1.z = f2bf(b.z); o1.w = f2bf(b.w);
    reinterpret_cast<ushort4*>(out)[i * 2 + 0] = o0;
    reinterpret_cast<ushort4*>(out)[i * 2 + 1] = o1;
}

// All weights (both layers) + layer-0 activation -> bf16 in one launch.
#define WI8 1048576  // 2*4096*1024/8
#define WO8 524288   // 2*1024*2048/8
#define WX8 49152    // 2*96*2048/8
#define WD8 32768    // 2*2048*64/8
#define AC8 262144   // TOK*1024/8
__global__ __launch_bounds__(256)
void cvt_all(const float* __restrict__ wi, const float* __restrict__ wo,
             const float* __restrict__ wx, const float* __restrict__ wd,
             const float* __restrict__ xin,
             unsigned short* __restrict__ wi_bf, unsigned short* __restrict__ wo_bf,
             unsigned short* __restrict__ wx_bf, unsigned short* __restrict__ wd_bf,
             unsigned short* __restrict__ act_bf) {
    int i = blockIdx.x * 256 + threadIdx.x;
    if (i < WI8) { cvt8(wi, wi_bf, i); return; }
    i -= WI8;
    if (i < WO8) { cvt8(wo, wo_bf, i); return; }
    i -= WO8;
    if (i < WX8) { cvt8(wx, wx_bf, i); return; }
    i -= WX8;
    if (i < WD8) { cvt8(wd, wd_bf, i); return; }
    i -= WD8;
    if (i < AC8) { cvt8(xin, act_bf, i); return; }
}

// ---------------------------------------------------------------------------
// bf16 MFMA GEMM, double-buffered LDS, counted vmcnt, swizzled LDS layout.
// C[M][N] = A[M][K] @ W[N][K]^T.  128x128 tile, BK=32, 4 waves, 16x16x32 MFMA.
// Split-K via blockIdx.z: K-slice [z*kLen,(z+1)*kLen), C += z*cSlice.
// EPI 3: bf16; EPI 4: bf16 softplus; EPI 5: bf16 guarded (n<Nw).
// ---------------------------------------------------------------------------
template <int EPI>
__global__ __launch_bounds__(256)
void gemm_bf16(const unsigned short* __restrict__ Ab, int lda,
               const unsigned short* __restrict__ Wb, int ldw,
               void* __restrict__ Cptr, int ldc, int kLen, int Nw,
               size_t cSlice, const float* __restrict__ bias) {
    __shared__ unsigned short As[2][128 * 32];
    __shared__ unsigned short Bs[2][128 * 32];
    const int tid = threadIdx.x;
    const int wave = tid >> 6, lane = tid & 63;
    const int wr = wave >> 1, wc = wave & 1;
    const int m0 = blockIdx.y * 128, n0 = blockIdx.x * 128;
    const int kbeg = blockIdx.z * kLen;
    const int r = lane & 15, kq = lane >> 4;
    const int nt = kLen >> 5;

    // staging: thread fills physical granules ch0=tid, ch1=256+tid of each
    // array; global source = inverse-swizzled logical (row, kq).
    const int ch0 = tid, ch1 = 256 + tid;
    const int g0 = ch0 >> 3, p0 = ch0 & 7, lp0 = p0 ^ (g0 & 7);
    const int srow0 = (g0 << 1) | (lp0 >> 2), skq0 = lp0 & 3;
    const int g1 = ch1 >> 3, p1 = ch1 & 7, lp1 = p1 ^ (g1 & 7);
    const int srow1 = (g1 << 1) | (lp1 >> 2), skq1 = lp1 & 3;
    const int wrow0 = min(n0 + srow0, Nw - 1);
    const int wrow1 = min(n0 + srow1, Nw - 1);

    auto stage = [&](int buf, int kt) {
        __builtin_amdgcn_global_load_lds(
            (const __attribute__((address_space(1))) void*)
                &Ab[(size_t)(m0 + srow0) * lda + kt + skq0 * 8],
            (__attribute__((address_space(3))) void*)&As[buf][ch0 * 8], 16, 0, 0);
        __builtin_amdgcn_global_load_lds(
            (const __attribute__((address_space(1))) void*)
                &Wb[(size_t)wrow0 * ldw + kt + skq0 * 8],
            (__attribute__((address_space(3))) void*)&Bs[buf][ch0 * 8], 16, 0, 0);
        __builtin_amdgcn_global_load_lds(
            (const __attribute__((address_space(1))) void*)
                &Ab[(size_t)(m0 + srow1) * lda + kt + skq1 * 8],
            (__attribute__((address_space(3))) void*)&As[buf][ch1 * 8], 16, 0, 0);
        __builtin_amdgcn_global_load_lds(
            (const __attribute__((address_space(1))) void*)
                &Wb[(size_t)wrow1 * ldw + kt + skq1 * 8],
            (__attribute__((address_space(3))) void*)&Bs[buf][ch1 * 8], 16, 0, 0);
    };

    // precomputed swizzled read offsets (ushort index), loop-invariant
    int aoff[4], boff[4];
#pragma unroll
    for (int f = 0; f < 4; ++f) {
        aoff[f] = swz_granule(wr * 64 + f * 16 + r, kq) * 8;
        boff[f] = swz_granule(wc * 64 + f * 16 + r, kq) * 8;
    }

    f32x4 acc[4][4] = {};
    stage(0, kbeg);
    for (int t = 0; t < nt; ++t) {
        const int cur = t & 1;
        if (t + 1 < nt) {
            stage(cur ^ 1, kbeg + (t + 1) * 32);
            asm volatile("s_waitcnt vmcnt(4)" ::: "memory");
        } else {
            asm volatile("s_waitcnt vmcnt(0)" ::: "memory");
        }
        __builtin_amdgcn_s_barrier();
        __builtin_amdgcn_sched_barrier(0);
        bf16x8 a[4], b[4];
#pragma unroll
        for (int f = 0; f < 4; ++f) {
            a[f] = *reinterpret_cast<const bf16x8*>(&As[cur][aoff[f]]);
            b[f] = *reinterpret_cast<const bf16x8*>(&Bs[cur][boff[f]]);
        }
#pragma unroll
        for (int fi = 0; fi < 4; ++fi)
#pragma unroll
            for (int fj = 0; fj < 4; ++fj)
                acc[fi][fj] = __builtin_amdgcn_mfma_f32_16x16x32_bf16(
                    a[fi], b[fj], acc[fi][fj], 0, 0, 0);
        __builtin_amdgcn_sched_barrier(0);
        asm volatile("s_waitcnt lgkmcnt(0)" ::: "memory");
        __builtin_amdgcn_s_barrier();
    }

    // C/D layout: col = lane&15, row = (lane>>4)*4 + reg (m89).
    const int cr = lane >> 4, cc = lane & 15;
#pragma unroll
    for (int fi = 0; fi < 4; ++fi)
#pragma unroll
        for (int fj = 0; fj < 4; ++fj)
#pragma unroll
            for (int p = 0; p < 4; ++p) {
                const int m = m0 + wr * 64 + fi * 16 + cr * 4 + p;
                const int n = n0 + wc * 64 + fj * 16 + cc;
                const float v = acc[fi][fj][p];
                if (EPI == 3) {
                    ((unsigned short*)Cptr)[(size_t)blockIdx.z * cSlice +
                                            (size_t)m * ldc + n] = f2bf(v);
                } else if (EPI == 4) {  // bf16 softplus store
                    ((unsigned short*)Cptr)[(size_t)m * ldc + n] =
                        f2bf(softplusf(v + bias[n]));
                } else {  // EPI 5: bf16 guarded store
                    if (n < Nw)
                        ((unsigned short*)Cptr)[(size_t)blockIdx.z * cSlice +
                                                (size_t)m * ldc + n] = f2bf(v);
                }
            }
}

// ---------------------------------------------------------------------------
// Causal depthwise conv1d (+bias) + SiLU; 8 channels/thread, bf16 in/out.
// ---------------------------------------------------------------------------
__global__ __launch_bounds__(256)
void conv_silu8(const unsigned short* __restrict__ xz_bf,
                const float* __restrict__ cw,   // [DINNER][DCONV]
                const float* __restrict__ cb,   // [DINNER]
                unsigned short* __restrict__ u_bf) {
    const int gid = blockIdx.x * 256 + threadIdx.x;  // TOK*256
    const int d8 = gid & 255;
    const int t = gid >> 8;
    const int l = t & (SEQ - 1);
    const int d0 = d8 * 8;

    float cwv[8][4];
#pragma unroll
    for (int j = 0; j < 8; ++j) {
        const float4 c = *reinterpret_cast<const float4*>(&cw[(d0 + j) * DCONV]);
        cwv[j][0] = c.x; cwv[j][1] = c.y; cwv[j][2] = c.z; cwv[j][3] = c.w;
    }
    float acc[8];
    {
        const float4 b0 = *reinterpret_cast<const float4*>(&cb[d0]);
        const float4 b1 = *reinterpret_cast<const float4*>(&cb[d0 + 4]);
        acc[0] = b0.x; acc[1] = b0.y; acc[2] = b0.z; acc[3] = b0.w;
        acc[4] = b1.x; acc[5] = b1.y; acc[6] = b1.z; acc[7] = b1.w;
    }
#pragma unroll
    for (int k = 0; k < DCONV; ++k) {
        const int li = l - (DCONV - 1) + k;
        if (li >= 0) {
            const ushort8 v = *reinterpret_cast<const ushort8*>(
                &xz_bf[(size_t)(t - (DCONV - 1) + k) * 4096 + d0]);
#pragma unroll
            for (int j = 0; j < 8; ++j)
                acc[j] = fmaf(cwv[j][k], bf2f(v[j]), acc[j]);
        }
    }
    ushort8 o;
#pragma unroll
    for (int j = 0; j < 8; ++j) o[j] = f2bf(siluf(acc[j]));
    *reinterpret_cast<ushort8*>(&u_bf[(size_t)t * DINNER + d0]) = o;
}

// ---------------------------------------------------------------------------
// Reduce x_proj K-split bf16 partials -> xdbl fp32 [TOK][96] + dt_bf [TOK][64]
// ---------------------------------------------------------------------------
__global__ __launch_bounds__(256)
void reduce_x(const unsigned short* __restrict__ part, float* __restrict__ xdbl,
              unsigned short* __restrict__ dt_bf) {
    const int i = blockIdx.x * 256 + threadIdx.x;  // over TOK*96
    if (i >= TOK * 96) return;
    float s = 0.f;
#pragma unroll
    for (int k = 0; k < KSX; ++k) s += bf2f(part[(size_t)k * (TOK * 96) + i]);
    xdbl[i] = s;
    const int t = i / 96, c = i - t * 96;
    if (c < DTRANK) dt_bf[t * DTRANK + c] = f2bf(s);
}

// ---------------------------------------------------------------------------
// Reduce out_proj K-split bf16 partials (4 elems/thread).
// MODE 0: -> bf16 activation; MODE 1: -> fp32 out + residual.
// ---------------------------------------------------------------------------
template <int MODE>
__global__ __launch_bounds__(256)
void reduce_out(const unsigned short* __restrict__ part,
                const float* __restrict__ resid, void* __restrict__ outp) {
    const int i = blockIdx.x * 256 + threadIdx.x;  // over TOK*DMODEL/4
    if (i >= TOK * DMODEL / 4) return;
    float s[4] = {0.f, 0.f, 0.f, 0.f};
#pragma unroll
    for (int k = 0; k < KSO; ++k) {
        const ushort4 p = reinterpret_cast<const ushort4*>(
            &part[(size_t)k * (TOK * DMODEL)])[i];
        s[0] += bf2f(p.x); s[1] += bf2f(p.y); s[2] += bf2f(p.z); s[3] += bf2f(p.w);
    }
    if (MODE == 0) {
        ushort4 o;
        o.x = f2bf(s[0]); o.y = f2bf(s[1]); o.z = f2bf(s[2]); o.w = f2bf(s[3]);
        reinterpret_cast<ushort4*>(outp)[i] = o;
    } else {
        const float4 rr = reinterpret_cast<const float4*>(resid)[i];
        float4 o;
        o.x = s[0] + rr.x; o.y = s[1] + rr.y; o.z = s[2] + rr.z; o.w = s[3] + rr.w;
        reinterpret_cast<float4*>(outp)[i] = o;
    }
}

// ---------------------------------------------------------------------------
// Fused chunk-parallel selective scan, single cooperative kernel:
//   phase 1: per-chunk local scan from h=0 -> hbuf/Pbuf (bf16)
//   grid.sync()
//   phase 2: serial prefix over chunks (1 thread per (b,d,n))
//   grid.sync()
//   phase 3: re-scan chunk from h_init, emit y with D-skip + silu(z) gate
// Grid: (DINNER/256, BATCH*NCHUNK), block 256 -> 512 blocks (2/CU, co-resident)
// ---------------------------------------------------------------------------
__device__ __forceinline__ void load_b16(const float* __restrict__ p, float* B) {
    const float4* bp = reinterpret_cast<const float4*>(p);
    const float4 b0 = bp[0], b1 = bp[1], b2 = bp[2], b3 = bp[3];
    B[0] = b0.x; B[1] = b0.y; B[2] = b0.z; B[3] = b0.w;
    B[4] = b1.x; B[5] = b1.y; B[6] = b1.z; B[7] = b1.w;
    B[8] = b2.x; B[9] = b2.y; B[10] = b2.z; B[11] = b2.w;
    B[12] = b3.x; B[13] = b3.y; B[14] = b3.z; B[15] = b3.w;
}
__device__ __forceinline__ void load_bf16x16(const unsigned short* __restrict__ p,
                                             float* B) {
    const ushort8 v0 = *reinterpret_cast<const ushort8*>(p);
    const ushort8 v1 = *reinterpret_cast<const ushort8*>(p + 8);
#pragma unroll
    for (int j = 0; j < 8; ++j) { B[j] = bf2f(v0[j]); B[8 + j] = bf2f(v1[j]); }
}
__device__ __forceinline__ void store_bf16x16(unsigned short* __restrict__ p,
                                              const float* B) {
    ushort8 v0, v1;
#pragma unroll
    for (int j = 0; j < 8; ++j) { v0[j] = f2bf(B[j]); v1[j] = f2bf(B[8 + j]); }
    *reinterpret_cast<ushort8*>(p) = v0;
    *reinterpret_cast<ushort8*>(p + 8) = v1;
}

__global__ __launch_bounds__(256)
void scan_fused(const unsigned short* __restrict__ delta_bf,
                const unsigned short* __restrict__ u_bf,
                const float* __restrict__ xdbl,
                const unsigned short* __restrict__ xz_bf,  // z at col 2048+d
                const float* __restrict__ A_log,
                const float* __restrict__ Dp,
                unsigned short* __restrict__ hbuf,
                unsigned short* __restrict__ Pbuf,
                unsigned short* __restrict__ yout) {
    cg::grid_group grid = cg::this_grid();
    const int b = blockIdx.y / NCHUNK;
    const int c = blockIdx.y % NCHUNK;
    const int d = blockIdx.x * 256 + threadIdx.x;
    const int t0 = b * SEQ + c * CLEN;

    float A_dn[16];
    load_b16(&A_log[d * DSTATE], A_dn);
#pragma unroll
    for (int n = 0; n < 16; ++n) A_dn[n] = -__expf(A_dn[n]);

    // ---------------- phase 1: local scan from h=0 ----------------
    {
        float h[16];
#pragma unroll
        for (int n = 0; n < 16; ++n) h[n] = 0.f;
        float sdlt = 0.f;

        float dltA, uvA, BA[16];
        float dltB, uvB, BB[16];
        dltA = bf2f(delta_bf[(size_t)t0 * DINNER + d]);
        uvA = bf2f(u_bf[(size_t)t0 * DINNER + d]);
        load_b16(&xdbl[(size_t)t0 * 96 + DTRANK], BA);

#define PSTEP(dlt_, uv_, Bc_)                              \
        {                                                  \
            const float du = (dlt_) * (uv_);               \
            sdlt += (dlt_);                                \
            _Pragma("unroll")                              \
            for (int n = 0; n < 16; ++n) {                 \
                const float dA = __expf((dlt_) * A_dn[n]); \
                h[n] = fmaf(dA, h[n], du * Bc_[n]);        \
            }                                              \
        }

        for (int l = 0; l < CLEN; l += 2) {
            const int t = t0 + l;
            dltB = bf2f(delta_bf[(size_t)(t + 1) * DINNER + d]);
            uvB = bf2f(u_bf[(size_t)(t + 1) * DINNER + d]);
            load_b16(&xdbl[(size_t)(t + 1) * 96 + DTRANK], BB);
            PSTEP(dltA, uvA, BA);
            if (l + 2 < CLEN) {
                dltA = bf2f(delta_bf[(size_t)(t + 2) * DINNER + d]);
                uvA = bf2f(u_bf[(size_t)(t + 2) * DINNER + d]);
                load_b16(&xdbl[(size_t)(t + 2) * 96 + DTRANK], BA);
            }
            PSTEP(dltB, uvB, BB);
        }
#undef PSTEP

        float P[16];
#pragma unroll
        for (int n = 0; n < 16; ++n) P[n] = __expf(sdlt * A_dn[n]);

        const size_t base = ((size_t)(b * NCHUNK + c) * DINNER + d) * DSTATE;
        store_bf16x16(&hbuf[base], h);
        store_bf16x16(&Pbuf[base], P);
    }

    __threadfence();
    grid.sync();

    // ---------------- phase 2: prefix over chunks ----------------
    {
        const int flat = (blockIdx.y * gridDim.x + blockIdx.x) * 256 + threadIdx.x;
        if (flat < BATCH * DINNER * DSTATE) {
            const int b2 = flat / (DINNER * DSTATE);
            const int dn = flat - b2 * (DINNER * DSTATE);
            const size_t base = (size_t)b2 * NCHUNK * DINNER * DSTATE + dn;
            float hv[NCHUNK], Pv[NCHUNK];
#pragma unroll
            for (int cc = 0; cc < NCHUNK; ++cc) {
                const size_t idx = base + (size_t)cc * (DINNER * DSTATE);
                hv[cc] = bf2f(hbuf[idx]);
                Pv[cc] = bf2f(Pbuf[idx]);
            }
            float hi = 0.f;
#pragma unroll
            for (int cc = 0; cc < NCHUNK; ++cc) {
                const size_t idx = base + (size_t)cc * (DINNER * DSTATE);
                hbuf[idx] = f2bf(hi);
                hi = fmaf(Pv[cc], hi, hv[cc]);
            }
        }
    }

    __threadfence();
    grid.sync();

    // ---------------- phase 3: final scan + gate ----------------
    {
        const float Dd = Dp[d];
        float h[16];
        load_bf16x16(&hbuf[((size_t)(b * NCHUNK + c) * DINNER + d) * DSTATE], h);

        float dltA, uvA, BA[16], CA[16];
        float dltB, uvB, BB[16], CB[16];
        dltA = bf2f(delta_bf[(size_t)t0 * DINNER + d]);
        uvA = bf2f(u_bf[(size_t)t0 * DINNER + d]);
        load_b16(&xdbl[(size_t)t0 * 96 + DTRANK], BA);
        load_b16(&xdbl[(size_t)t0 * 96 + DTRANK + DSTATE], CA);

#define FSTEP(t_, dlt_, uv_, Bc_, Cc_)                          \
        {                                                       \
            const float du = (dlt_) * (uv_);                    \
            _Pragma("unroll")                                   \
            for (int n = 0; n < 16; ++n) {                      \
                const float dA = __expf((dlt_) * A_dn[n]);      \
                h[n] = fmaf(dA, h[n], du * Bc_[n]);             \
            }                                                   \
            float s0 = 0.f, s1 = 0.f, s2 = 0.f, s3 = 0.f;       \
            _Pragma("unroll")                                   \
            for (int q = 0; q < 4; ++q) {                       \
                s0 = fmaf(h[q*4+0], Cc_[q*4+0], s0);            \
                s1 = fmaf(h[q*4+1], Cc_[q*4+1], s1);            \
                s2 = fmaf(h[q*4+2], Cc_[q*4+2], s2);            \
                s3 = fmaf(h[q*4+3], Cc_[q*4+3], s3);            \
            }                                                   \
            const float zv = bf2f(xz_bf[(size_t)(t_) * 4096 + 2048 + d]); \
            const float y = (s0 + s1) + (s2 + s3) + (uv_) * Dd; \
            yout[(size_t)(t_) * DINNER + d] = f2bf(y * siluf(zv)); \
        }

        for (int l = 0; l < CLEN; l += 2) {
            const int t = t0 + l;
            dltB = bf2f(delta_bf[(size_t)(t + 1) * DINNER + d]);
            uvB = bf2f(u_bf[(size_t)(t + 1) * DINNER + d]);
            load_b16(&xdbl[(size_t)(t + 1) * 96 + DTRANK], BB);
            load_b16(&xdbl[(size_t)(t + 1) * 96 + DTRANK + DSTATE], CB);
            FSTEP(t, dltA, uvA, BA, CA);
            if (l + 2 < CLEN) {
                dltA = bf2f(delta_bf[(size_t)(t + 2) * DINNER + d]);
                uvA = bf2f(u_bf[(size_t)(t + 2) * DINNER + d]);
                load_b16(&xdbl[(size_t)(t + 2) * 96 + DTRANK], BA);
                load_b16(&xdbl[(size_t)(t + 2) * 96 + DTRANK + DSTATE], CA);
            }
            FSTEP(t + 1, dltB, uvB, BB, CB);
        }
#undef FSTEP
    }
}

// ---------------------------------------------------------------------------
extern "C" void kernel_launch(void* const* d_in, const int* in_sizes, int n_in,
                              void* d_out, int out_size, void* d_ws, size_t ws_size,
                              hipStream_t stream) {
    const float* x          = (const float*)d_in[0];
    const float* in_proj_w  = (const float*)d_in[1];
    const float* conv_w     = (const float*)d_in[2];
    const float* conv_b     = (const float*)d_in[3];
    const float* x_proj_w   = (const float*)d_in[4];
    const float* dt_proj_w  = (const float*)d_in[5];
    const float* dt_proj_b  = (const float*)d_in[6];
    const float* A_log      = (const float*)d_in[7];
    const float* Dp         = (const float*)d_in[8];
    const float* out_proj_w = (const float*)d_in[9];
    float* out = (float*)d_out;

    // workspace layout
    float* ws = (float*)d_ws;
    float* xdbl  = ws;                           // 196,608 f
    unsigned short* us = (unsigned short*)(xdbl + 196608);
    unsigned short* xpart  = us;                 // KSX*TOK*96 = 3,145,728 (bf16)
    unsigned short* hbuf   = xpart + 3145728;    // 2,097,152
    unsigned short* Pbuf   = hbuf + 2097152;     // 2,097,152
    unsigned short* opart  = Pbuf + 2097152;     // KSO*TOK*1024 = 8,388,608
    unsigned short* wi_bf  = opart + 8388608;    // 8,388,608
    unsigned short* wo_bf  = wi_bf + 8388608;    // 4,194,304
    unsigned short* wx_bf  = wo_bf + 4194304;    // 393,216
    unsigned short* wd_bf  = wx_bf + 393216;     // 262,144
    unsigned short* xz_bf  = wd_bf + 262144;     // TOK*4096 = 8,388,608
    unsigned short* u_bf   = xz_bf + 8388608;    // 4,194,304
    unsigned short* dlt_bf = u_bf  + 4194304;    // 4,194,304
    unsigned short* act_bf = dlt_bf + 4194304;   // 2,097,152
    unsigned short* y_bf   = act_bf + 2097152;   // 4,194,304
    unsigned short* dt_bf  = y_bf  + 4194304;    // 131,072

    // one-time conversions (weights both layers + layer-0 act)
    cvt_all<<<(WI8 + WO8 + WX8 + WD8 + AC8 + 255) / 256, 256, 0, stream>>>(
        in_proj_w, out_proj_w, x_proj_w, dt_proj_w, x,
        wi_bf, wo_bf, wx_bf, wd_bf, act_bf);

    for (int layer = 0; layer < NLAYERS; ++layer) {
        const unsigned short* Wi = wi_bf + (size_t)layer * (2 * DINNER) * DMODEL;
        const unsigned short* Wo = wo_bf + (size_t)layer * DMODEL * DINNER;
        const unsigned short* Wx = wx_bf + (size_t)layer * 96 * DINNER;
        const unsigned short* Wd = wd_bf + (size_t)layer * DINNER * DTRANK;
        const float* cw = conv_w    + (size_t)layer * DINNER * DCONV;
        const float* cb = conv_b    + (size_t)layer * DINNER;
        const float* bd = dt_proj_b + (size_t)layer * DINNER;
        const float* Al = A_log     + (size_t)layer * DINNER * DSTATE;
        const float* Dl = Dp        + (size_t)layer * DINNER;

        // 1. xz = act @ W_in^T -> bf16  (TOK x 4096, K=1024)
        {
            dim3 grid(4096 / 128, TOK / 128, 1);
            gemm_bf16<3><<<grid, 256, 0, stream>>>(act_bf, DMODEL, Wi, DMODEL,
                                                   xz_bf, 2 * DINNER, DMODEL,
                                                   2 * DINNER, 0, nullptr);
        }
        // 2. u = silu(conv(xc)+b) -> u_bf
        conv_silu8<<<(TOK * 256) / 256, 256, 0, stream>>>(xz_bf, cw, cb, u_bf);
        // 3. x_dbl partials = u_bf @ Wx^T (TOK x 96, K=2048, split-K16) -> bf16
        {
            dim3 grid(1, TOK / 128, KSX);
            gemm_bf16<5><<<grid, 256, 0, stream>>>(u_bf, DINNER, Wx, DINNER,
                                                   xpart, 96, DINNER / KSX, 96,
                                                   (size_t)TOK * 96, nullptr);
            reduce_x<<<(TOK * 96 + 255) / 256, 256, 0, stream>>>(xpart, xdbl, dt_bf);
        }
        // 4. delta = softplus(dt_bf @ Wd^T + b) -> bf16  (TOK x 2048, K=64)
        {
            dim3 grid(DINNER / 128, TOK / 128, 1);
            gemm_bf16<4><<<grid, 256, 0, stream>>>(dt_bf, DTRANK, Wd, DTRANK,
                                                   dlt_bf, DINNER, DTRANK, DINNER,
                                                   0, bd);
        }
        // 5. fused chunk-parallel scan (1 cooperative dispatch) -> y_bf
        {
            void* args[] = {(void*)&dlt_bf, (void*)&u_bf, (void*)&xdbl,
                            (void*)&xz_bf, (void*)&Al, (void*)&Dl,
                            (void*)&hbuf, (void*)&Pbuf, (void*)&y_bf};
            hipLaunchCooperativeKernel((void*)scan_fused,
                                       dim3(DINNER / 256, BATCH * NCHUNK),
                                       dim3(256), args, 0, stream);
        }
        // 6. out partials = y_bf @ Wo^T (TOK x 1024, K=2048, split-K4) -> reduce
        {
            dim3 grid(DMODEL / 128, TOK / 128, KSO);
            gemm_bf16<3><<<grid, 256, 0, stream>>>(y_bf, DINNER, Wo, DINNER,
                                                   opart, DMODEL, DINNER / KSO,
                                                   DMODEL, (size_t)TOK * DMODEL,
                                                   nullptr);
            const int nred = TOK * DMODEL / 4;
            if (layer == NLAYERS - 1) {
                reduce_out<1><<<(nred + 255) / 256, 256, 0, stream>>>(opart, x, out);
            } else {
                reduce_out<0><<<(nred + 255) / 256, 256, 0, stream>>>(opart, nullptr,
                                                                      act_bf);
            }
        }
    }
}

// Round 14
// 318.764 us; speedup vs baseline: 2.5274x; 2.5274x over previous
//
#include <hip/hip_runtime.h>
#include <hip/hip_bf16.h>

// Problem constants
#define NLAYERS 2
#define DMODEL 1024
#define DINNER 2048
#define DSTATE 16
#define DCONV 4
#define DTRANK 64
#define BATCH 2
#define SEQ 1024
#define TOK (BATCH * SEQ)   // 2048 tokens

#define NCHUNK 32
#define CLEN (SEQ / NCHUNK)  // 32
#define KSX 16               // x_proj K-split
#define KSO 4                // out_proj K-split

typedef short bf16x8 __attribute__((ext_vector_type(8)));
typedef float f32x4 __attribute__((ext_vector_type(4)));
typedef unsigned short ushort8 __attribute__((ext_vector_type(8)));

__device__ __forceinline__ float softplusf(float x) {
    return (x > 20.f) ? x : log1pf(__expf(x));
}
__device__ __forceinline__ float siluf(float x) {
    return x / (1.f + __expf(-x));
}
__device__ __forceinline__ unsigned short f2bf(float f) {
    union { float f; unsigned int u; } v; v.f = f;
    const unsigned int r = (v.u + 0x7FFFu + ((v.u >> 16) & 1u)) >> 16;
    return (unsigned short)r;
}
__device__ __forceinline__ float bf2f(unsigned short s) {
    union { unsigned int u; float f; } v; v.u = ((unsigned int)s) << 16;
    return v.f;
}

// LDS swizzle (16-B granules, rows of 32 bf16 = 4 granules, involution):
// physical granule = (row>>1)*8 + ((((row&1)<<2)|kq) ^ ((row>>1)&7))
__device__ __forceinline__ int swz_granule(int row, int kq) {
    return (row >> 1) * 8 + ((((row & 1) << 2) | kq) ^ ((row >> 1) & 7));
}

// ---------------------------------------------------------------------------
// fp32 -> bf16, 8 elems/thread (helper)
// ---------------------------------------------------------------------------
__device__ __forceinline__ void cvt8(const float* __restrict__ in,
                                     unsigned short* __restrict__ out, int i) {
    const float4 a = reinterpret_cast<const float4*>(in)[i * 2 + 0];
    const float4 b = reinterpret_cast<const float4*>(in)[i * 2 + 1];
    ushort4 o0, o1;
    o0.x = f2bf(a.x); o0.y = f2bf(a.y); o0.z = f2bf(a.z); o0.w = f2bf(a.w);
    o1.x = f2bf(b.x); o1.y = f2bf(b.y); o1.z = f2bf(b.z); o1.w = f2bf(b.w);
    reinterpret_cast<ushort4*>(out)[i * 2 + 0] = o0;
    reinterpret_cast<ushort4*>(out)[i * 2 + 1] = o1;
}

// All weights (both layers) + layer-0 activation -> bf16 in one launch.
#define WI8 1048576  // 2*4096*1024/8
#define WO8 524288   // 2*1024*2048/8
#define WX8 49152    // 2*96*2048/8
#define WD8 32768    // 2*2048*64/8
#define AC8 262144   // TOK*1024/8
__global__ __launch_bounds__(256)
void cvt_all(const float* __restrict__ wi, const float* __restrict__ wo,
             const float* __restrict__ wx, const float* __restrict__ wd,
             const float* __restrict__ xin,
             unsigned short* __restrict__ wi_bf, unsigned short* __restrict__ wo_bf,
             unsigned short* __restrict__ wx_bf, unsigned short* __restrict__ wd_bf,
             unsigned short* __restrict__ act_bf) {
    int i = blockIdx.x * 256 + threadIdx.x;
    if (i < WI8) { cvt8(wi, wi_bf, i); return; }
    i -= WI8;
    if (i < WO8) { cvt8(wo, wo_bf, i); return; }
    i -= WO8;
    if (i < WX8) { cvt8(wx, wx_bf, i); return; }
    i -= WX8;
    if (i < WD8) { cvt8(wd, wd_bf, i); return; }
    i -= WD8;
    if (i < AC8) { cvt8(xin, act_bf, i); return; }
}

// ---------------------------------------------------------------------------
// bf16 MFMA GEMM, double-buffered LDS, counted vmcnt, SWIZZLED LDS layout:
// C[M][N] = A[M][K] @ W[N][K]^T.  128x128 tile, BK=32, 4 waves, 16x16x32 MFMA.
// Staging writes lane-linear LDS; the GLOBAL source address is permuted by
// the inverse swizzle; ds_reads use the same swizzle -> conflict-free (2-way).
// Per K-tile: stage(next) -> vmcnt(4) -> s_barrier -> ds_read+MFMA ->
// lgkmcnt(0) -> s_barrier. Split-K via blockIdx.z; Nw clamps/guards W rows.
// EPI 0: fp32 guarded; EPI 3: bf16; EPI 4: bf16 softplus; EPI 5: bf16 guarded.
// ---------------------------------------------------------------------------
template <int EPI>
__global__ __launch_bounds__(256)
void gemm_bf16(const unsigned short* __restrict__ Ab, int lda,
               const unsigned short* __restrict__ Wb, int ldw,
               void* __restrict__ Cptr, int ldc, int kLen, int Nw,
               size_t cSlice, const float* __restrict__ bias) {
    __shared__ unsigned short As[2][128 * 32];
    __shared__ unsigned short Bs[2][128 * 32];
    const int tid = threadIdx.x;
    const int wave = tid >> 6, lane = tid & 63;
    const int wr = wave >> 1, wc = wave & 1;
    const int m0 = blockIdx.y * 128, n0 = blockIdx.x * 128;
    const int kbeg = blockIdx.z * kLen;
    const int r = lane & 15, kq = lane >> 4;
    const int nt = kLen >> 5;

    // staging: thread fills physical granules ch0=tid, ch1=256+tid of each
    // array; global source = inverse-swizzled logical (row, kq).
    const int ch0 = tid, ch1 = 256 + tid;
    const int g0 = ch0 >> 3, p0 = ch0 & 7, lp0 = p0 ^ (g0 & 7);
    const int srow0 = (g0 << 1) | (lp0 >> 2), skq0 = lp0 & 3;
    const int g1 = ch1 >> 3, p1 = ch1 & 7, lp1 = p1 ^ (g1 & 7);
    const int srow1 = (g1 << 1) | (lp1 >> 2), skq1 = lp1 & 3;
    const int wrow0 = min(n0 + srow0, Nw - 1);
    const int wrow1 = min(n0 + srow1, Nw - 1);

    auto stage = [&](int buf, int kt) {
        __builtin_amdgcn_global_load_lds(
            (const __attribute__((address_space(1))) void*)
                &Ab[(size_t)(m0 + srow0) * lda + kt + skq0 * 8],
            (__attribute__((address_space(3))) void*)&As[buf][ch0 * 8], 16, 0, 0);
        __builtin_amdgcn_global_load_lds(
            (const __attribute__((address_space(1))) void*)
                &Wb[(size_t)wrow0 * ldw + kt + skq0 * 8],
            (__attribute__((address_space(3))) void*)&Bs[buf][ch0 * 8], 16, 0, 0);
        __builtin_amdgcn_global_load_lds(
            (const __attribute__((address_space(1))) void*)
                &Ab[(size_t)(m0 + srow1) * lda + kt + skq1 * 8],
            (__attribute__((address_space(3))) void*)&As[buf][ch1 * 8], 16, 0, 0);
        __builtin_amdgcn_global_load_lds(
            (const __attribute__((address_space(1))) void*)
                &Wb[(size_t)wrow1 * ldw + kt + skq1 * 8],
            (__attribute__((address_space(3))) void*)&Bs[buf][ch1 * 8], 16, 0, 0);
    };

    // precomputed swizzled read offsets (ushort index), loop-invariant
    int aoff[4], boff[4];
#pragma unroll
    for (int f = 0; f < 4; ++f) {
        aoff[f] = swz_granule(wr * 64 + f * 16 + r, kq) * 8;
        boff[f] = swz_granule(wc * 64 + f * 16 + r, kq) * 8;
    }

    f32x4 acc[4][4] = {};
    stage(0, kbeg);
    for (int t = 0; t < nt; ++t) {
        const int cur = t & 1;
        if (t + 1 < nt) {
            stage(cur ^ 1, kbeg + (t + 1) * 32);
            asm volatile("s_waitcnt vmcnt(4)" ::: "memory");
        } else {
            asm volatile("s_waitcnt vmcnt(0)" ::: "memory");
        }
        __builtin_amdgcn_s_barrier();
        __builtin_amdgcn_sched_barrier(0);
        bf16x8 a[4], b[4];
#pragma unroll
        for (int f = 0; f < 4; ++f) {
            a[f] = *reinterpret_cast<const bf16x8*>(&As[cur][aoff[f]]);
            b[f] = *reinterpret_cast<const bf16x8*>(&Bs[cur][boff[f]]);
        }
#pragma unroll
        for (int fi = 0; fi < 4; ++fi)
#pragma unroll
            for (int fj = 0; fj < 4; ++fj)
                acc[fi][fj] = __builtin_amdgcn_mfma_f32_16x16x32_bf16(
                    a[fi], b[fj], acc[fi][fj], 0, 0, 0);
        __builtin_amdgcn_sched_barrier(0);
        asm volatile("s_waitcnt lgkmcnt(0)" ::: "memory");
        __builtin_amdgcn_s_barrier();
    }

    // C/D layout: col = lane&15, row = (lane>>4)*4 + reg (m89).
    const int cr = lane >> 4, cc = lane & 15;
#pragma unroll
    for (int fi = 0; fi < 4; ++fi)
#pragma unroll
        for (int fj = 0; fj < 4; ++fj)
#pragma unroll
            for (int p = 0; p < 4; ++p) {
                const int m = m0 + wr * 64 + fi * 16 + cr * 4 + p;
                const int n = n0 + wc * 64 + fj * 16 + cc;
                const float v = acc[fi][fj][p];
                if (EPI == 0) {
                    if (n < Nw)
                        ((float*)Cptr)[(size_t)blockIdx.z * cSlice +
                                       (size_t)m * ldc + n] = v;
                } else if (EPI == 3) {
                    ((unsigned short*)Cptr)[(size_t)blockIdx.z * cSlice +
                                            (size_t)m * ldc + n] = f2bf(v);
                } else if (EPI == 4) {  // bf16 softplus store
                    ((unsigned short*)Cptr)[(size_t)m * ldc + n] =
                        f2bf(softplusf(v + bias[n]));
                } else {  // EPI 5: bf16 guarded store
                    if (n < Nw)
                        ((unsigned short*)Cptr)[(size_t)blockIdx.z * cSlice +
                                                (size_t)m * ldc + n] = f2bf(v);
                }
            }
}

// ---------------------------------------------------------------------------
// Causal depthwise conv1d (+bias) + SiLU; 8 channels/thread, bf16 in/out.
// ---------------------------------------------------------------------------
__global__ __launch_bounds__(256)
void conv_silu8(const unsigned short* __restrict__ xz_bf,
                const float* __restrict__ cw,   // [DINNER][DCONV]
                const float* __restrict__ cb,   // [DINNER]
                unsigned short* __restrict__ u_bf) {
    const int gid = blockIdx.x * 256 + threadIdx.x;  // TOK*256
    const int d8 = gid & 255;
    const int t = gid >> 8;
    const int l = t & (SEQ - 1);
    const int d0 = d8 * 8;

    float cwv[8][4];
#pragma unroll
    for (int j = 0; j < 8; ++j) {
        const float4 c = *reinterpret_cast<const float4*>(&cw[(d0 + j) * DCONV]);
        cwv[j][0] = c.x; cwv[j][1] = c.y; cwv[j][2] = c.z; cwv[j][3] = c.w;
    }
    float acc[8];
    {
        const float4 b0 = *reinterpret_cast<const float4*>(&cb[d0]);
        const float4 b1 = *reinterpret_cast<const float4*>(&cb[d0 + 4]);
        acc[0] = b0.x; acc[1] = b0.y; acc[2] = b0.z; acc[3] = b0.w;
        acc[4] = b1.x; acc[5] = b1.y; acc[6] = b1.z; acc[7] = b1.w;
    }
#pragma unroll
    for (int k = 0; k < DCONV; ++k) {
        const int li = l - (DCONV - 1) + k;
        if (li >= 0) {
            const ushort8 v = *reinterpret_cast<const ushort8*>(
                &xz_bf[(size_t)(t - (DCONV - 1) + k) * 4096 + d0]);
#pragma unroll
            for (int j = 0; j < 8; ++j)
                acc[j] = fmaf(cwv[j][k], bf2f(v[j]), acc[j]);
        }
    }
    ushort8 o;
#pragma unroll
    for (int j = 0; j < 8; ++j) o[j] = f2bf(siluf(acc[j]));
    *reinterpret_cast<ushort8*>(&u_bf[(size_t)t * DINNER + d0]) = o;
}

// ---------------------------------------------------------------------------
// Reduce x_proj K-split bf16 partials -> xdbl fp32 [TOK][96] + dt_bf [TOK][64]
// ---------------------------------------------------------------------------
__global__ __launch_bounds__(256)
void reduce_x(const unsigned short* __restrict__ part, float* __restrict__ xdbl,
              unsigned short* __restrict__ dt_bf) {
    const int i = blockIdx.x * 256 + threadIdx.x;  // over TOK*96
    if (i >= TOK * 96) return;
    float s = 0.f;
#pragma unroll
    for (int k = 0; k < KSX; ++k) s += bf2f(part[(size_t)k * (TOK * 96) + i]);
    xdbl[i] = s;
    const int t = i / 96, c = i - t * 96;
    if (c < DTRANK) dt_bf[t * DTRANK + c] = f2bf(s);
}

// ---------------------------------------------------------------------------
// Reduce out_proj K-split bf16 partials (4 elems/thread).
// MODE 0: -> bf16 activation; MODE 1: -> fp32 out + residual.
// ---------------------------------------------------------------------------
template <int MODE>
__global__ __launch_bounds__(256)
void reduce_out(const unsigned short* __restrict__ part,
                const float* __restrict__ resid, void* __restrict__ outp) {
    const int i = blockIdx.x * 256 + threadIdx.x;  // over TOK*DMODEL/4
    if (i >= TOK * DMODEL / 4) return;
    float s[4] = {0.f, 0.f, 0.f, 0.f};
#pragma unroll
    for (int k = 0; k < KSO; ++k) {
        const ushort4 p = reinterpret_cast<const ushort4*>(
            &part[(size_t)k * (TOK * DMODEL)])[i];
        s[0] += bf2f(p.x); s[1] += bf2f(p.y); s[2] += bf2f(p.z); s[3] += bf2f(p.w);
    }
    if (MODE == 0) {
        ushort4 o;
        o.x = f2bf(s[0]); o.y = f2bf(s[1]); o.z = f2bf(s[2]); o.w = f2bf(s[3]);
        reinterpret_cast<ushort4*>(outp)[i] = o;
    } else {
        const float4 rr = reinterpret_cast<const float4*>(resid)[i];
        float4 o;
        o.x = s[0] + rr.x; o.y = s[1] + rr.y; o.z = s[2] + rr.z; o.w = s[3] + rr.w;
        reinterpret_cast<float4*>(outp)[i] = o;
    }
}

// ---------------------------------------------------------------------------
// Chunk-parallel selective scan, register-state (16 states/thread), bf16 ins.
// hbuf/Pbuf stored in bf16 (fp32 math inside).
// ---------------------------------------------------------------------------
__device__ __forceinline__ void load_b16(const float* __restrict__ p, float* B) {
    const float4* bp = reinterpret_cast<const float4*>(p);
    const float4 b0 = bp[0], b1 = bp[1], b2 = bp[2], b3 = bp[3];
    B[0] = b0.x; B[1] = b0.y; B[2] = b0.z; B[3] = b0.w;
    B[4] = b1.x; B[5] = b1.y; B[6] = b1.z; B[7] = b1.w;
    B[8] = b2.x; B[9] = b2.y; B[10] = b2.z; B[11] = b2.w;
    B[12] = b3.x; B[13] = b3.y; B[14] = b3.z; B[15] = b3.w;
}
__device__ __forceinline__ void load_bf16x16(const unsigned short* __restrict__ p,
                                             float* B) {
    const ushort8 v0 = *reinterpret_cast<const ushort8*>(p);
    const ushort8 v1 = *reinterpret_cast<const ushort8*>(p + 8);
#pragma unroll
    for (int j = 0; j < 8; ++j) { B[j] = bf2f(v0[j]); B[8 + j] = bf2f(v1[j]); }
}
__device__ __forceinline__ void store_bf16x16(unsigned short* __restrict__ p,
                                              const float* B) {
    ushort8 v0, v1;
#pragma unroll
    for (int j = 0; j < 8; ++j) { v0[j] = f2bf(B[j]); v1[j] = f2bf(B[8 + j]); }
    *reinterpret_cast<ushort8*>(p) = v0;
    *reinterpret_cast<ushort8*>(p + 8) = v1;
}

__global__ __launch_bounds__(256)
void scan_partial(const unsigned short* __restrict__ delta_bf,
                  const unsigned short* __restrict__ u_bf,
                  const float* __restrict__ xdbl,
                  const float* __restrict__ A_log,
                  unsigned short* __restrict__ hbuf,
                  unsigned short* __restrict__ Pbuf) {
    const int b = blockIdx.y / NCHUNK;
    const int c = blockIdx.y % NCHUNK;
    const int d = blockIdx.x * 256 + threadIdx.x;
    const int t0 = b * SEQ + c * CLEN;

    float A_dn[16];
    load_b16(&A_log[d * DSTATE], A_dn);
#pragma unroll
    for (int n = 0; n < 16; ++n) A_dn[n] = -__expf(A_dn[n]);

    float h[16];
#pragma unroll
    for (int n = 0; n < 16; ++n) h[n] = 0.f;
    float sdlt = 0.f;  // P[n] = exp(A_dn[n] * sum(dlt))

    float dltA, uvA, BA[16];
    float dltB, uvB, BB[16];
    dltA = bf2f(delta_bf[(size_t)t0 * DINNER + d]);
    uvA = bf2f(u_bf[(size_t)t0 * DINNER + d]);
    load_b16(&xdbl[(size_t)t0 * 96 + DTRANK], BA);

#define PSTEP(dlt_, uv_, Bc_)                              \
    {                                                      \
        const float du = (dlt_) * (uv_);                   \
        sdlt += (dlt_);                                    \
        _Pragma("unroll")                                  \
        for (int n = 0; n < 16; ++n) {                     \
            const float dA = __expf((dlt_) * A_dn[n]);     \
            h[n] = fmaf(dA, h[n], du * Bc_[n]);            \
        }                                                  \
    }

    for (int l = 0; l < CLEN; l += 2) {
        const int t = t0 + l;
        dltB = bf2f(delta_bf[(size_t)(t + 1) * DINNER + d]);
        uvB = bf2f(u_bf[(size_t)(t + 1) * DINNER + d]);
        load_b16(&xdbl[(size_t)(t + 1) * 96 + DTRANK], BB);
        PSTEP(dltA, uvA, BA);
        if (l + 2 < CLEN) {
            dltA = bf2f(delta_bf[(size_t)(t + 2) * DINNER + d]);
            uvA = bf2f(u_bf[(size_t)(t + 2) * DINNER + d]);
            load_b16(&xdbl[(size_t)(t + 2) * 96 + DTRANK], BA);
        }
        PSTEP(dltB, uvB, BB);
    }
#undef PSTEP

    float P[16];
#pragma unroll
    for (int n = 0; n < 16; ++n) P[n] = __expf(sdlt * A_dn[n]);

    const size_t base = ((size_t)(b * NCHUNK + c) * DINNER + d) * DSTATE;
    store_bf16x16(&hbuf[base], h);
    store_bf16x16(&Pbuf[base], P);
}

__global__ __launch_bounds__(256)
void scan_combine(unsigned short* __restrict__ hbuf,
                  const unsigned short* __restrict__ Pbuf) {
    const int gid = blockIdx.x * 256 + threadIdx.x;  // over BATCH*DINNER*DSTATE
    const int b = gid / (DINNER * DSTATE);
    const int dn = gid - b * (DINNER * DSTATE);
    const size_t base = (size_t)b * NCHUNK * DINNER * DSTATE + dn;
    // parallel load phase (all independent)
    float hv[NCHUNK], Pv[NCHUNK];
#pragma unroll
    for (int c = 0; c < NCHUNK; ++c) {
        const size_t idx = base + (size_t)c * (DINNER * DSTATE);
        hv[c] = bf2f(hbuf[idx]);
        Pv[c] = bf2f(Pbuf[idx]);
    }
    // serial prefix + store
    float hi = 0.f;
#pragma unroll
    for (int c = 0; c < NCHUNK; ++c) {
        const size_t idx = base + (size_t)c * (DINNER * DSTATE);
        hbuf[idx] = f2bf(hi);
        hi = fmaf(Pv[c], hi, hv[c]);
    }
}

__global__ __launch_bounds__(256)
void scan_final(const unsigned short* __restrict__ delta_bf,
                const unsigned short* __restrict__ u_bf,
                const float* __restrict__ xdbl,
                const unsigned short* __restrict__ xz_bf,  // z at col 2048+d
                const float* __restrict__ A_log,
                const float* __restrict__ Dp,
                const unsigned short* __restrict__ hbuf,
                unsigned short* __restrict__ yout) {
    const int b = blockIdx.y / NCHUNK;
    const int c = blockIdx.y % NCHUNK;
    const int d = blockIdx.x * 256 + threadIdx.x;
    const int t0 = b * SEQ + c * CLEN;

    float A_dn[16];
    load_b16(&A_log[d * DSTATE], A_dn);
#pragma unroll
    for (int n = 0; n < 16; ++n) A_dn[n] = -__expf(A_dn[n]);
    const float Dd = Dp[d];

    float h[16];
    load_bf16x16(&hbuf[((size_t)(b * NCHUNK + c) * DINNER + d) * DSTATE], h);

    float dltA, uvA, BA[16], CA[16];
    float dltB, uvB, BB[16], CB[16];
    dltA = bf2f(delta_bf[(size_t)t0 * DINNER + d]);
    uvA = bf2f(u_bf[(size_t)t0 * DINNER + d]);
    load_b16(&xdbl[(size_t)t0 * 96 + DTRANK], BA);
    load_b16(&xdbl[(size_t)t0 * 96 + DTRANK + DSTATE], CA);

#define FSTEP(t_, dlt_, uv_, Bc_, Cc_)                          \
    {                                                           \
        const float du = (dlt_) * (uv_);                        \
        _Pragma("unroll")                                       \
        for (int n = 0; n < 16; ++n) {                          \
            const float dA = __expf((dlt_) * A_dn[n]);          \
            h[n] = fmaf(dA, h[n], du * Bc_[n]);                 \
        }                                                       \
        float s0 = 0.f, s1 = 0.f, s2 = 0.f, s3 = 0.f;           \
        _Pragma("unroll")                                       \
        for (int q = 0; q < 4; ++q) {                           \
            s0 = fmaf(h[q*4+0], Cc_[q*4+0], s0);                \
            s1 = fmaf(h[q*4+1], Cc_[q*4+1], s1);                \
            s2 = fmaf(h[q*4+2], Cc_[q*4+2], s2);                \
            s3 = fmaf(h[q*4+3], Cc_[q*4+3], s3);                \
        }                                                       \
        const float zv = bf2f(xz_bf[(size_t)(t_) * 4096 + 2048 + d]); \
        const float y = (s0 + s1) + (s2 + s3) + (uv_) * Dd;     \
        yout[(size_t)(t_) * DINNER + d] = f2bf(y * siluf(zv));  \
    }

    for (int l = 0; l < CLEN; l += 2) {
        const int t = t0 + l;
        dltB = bf2f(delta_bf[(size_t)(t + 1) * DINNER + d]);
        uvB = bf2f(u_bf[(size_t)(t + 1) * DINNER + d]);
        load_b16(&xdbl[(size_t)(t + 1) * 96 + DTRANK], BB);
        load_b16(&xdbl[(size_t)(t + 1) * 96 + DTRANK + DSTATE], CB);
        FSTEP(t, dltA, uvA, BA, CA);
        if (l + 2 < CLEN) {
            dltA = bf2f(delta_bf[(size_t)(t + 2) * DINNER + d]);
            uvA = bf2f(u_bf[(size_t)(t + 2) * DINNER + d]);
            load_b16(&xdbl[(size_t)(t + 2) * 96 + DTRANK], BA);
            load_b16(&xdbl[(size_t)(t + 2) * 96 + DTRANK + DSTATE], CA);
        }
        FSTEP(t + 1, dltB, uvB, BB, CB);
    }
#undef FSTEP
}

// ---------------------------------------------------------------------------
extern "C" void kernel_launch(void* const* d_in, const int* in_sizes, int n_in,
                              void* d_out, int out_size, void* d_ws, size_t ws_size,
                              hipStream_t stream) {
    const float* x          = (const float*)d_in[0];
    const float* in_proj_w  = (const float*)d_in[1];
    const float* conv_w     = (const float*)d_in[2];
    const float* conv_b     = (const float*)d_in[3];
    const float* x_proj_w   = (const float*)d_in[4];
    const float* dt_proj_w  = (const float*)d_in[5];
    const float* dt_proj_b  = (const float*)d_in[6];
    const float* A_log      = (const float*)d_in[7];
    const float* Dp         = (const float*)d_in[8];
    const float* out_proj_w = (const float*)d_in[9];
    float* out = (float*)d_out;

    // workspace layout
    float* ws = (float*)d_ws;
    float* xdbl  = ws;                           // 196,608 f
    unsigned short* us = (unsigned short*)(xdbl + 196608);
    unsigned short* xpart  = us;                 // KSX*TOK*96 = 3,145,728 (bf16)
    unsigned short* hbuf   = xpart + 3145728;    // 2,097,152
    unsigned short* Pbuf   = hbuf + 2097152;     // 2,097,152
    unsigned short* opart  = Pbuf + 2097152;     // KSO*TOK*1024 = 8,388,608
    unsigned short* wi_bf  = opart + 8388608;    // 8,388,608
    unsigned short* wo_bf  = wi_bf + 8388608;    // 4,194,304
    unsigned short* wx_bf  = wo_bf + 4194304;    // 393,216
    unsigned short* wd_bf  = wx_bf + 393216;     // 262,144
    unsigned short* xz_bf  = wd_bf + 262144;     // TOK*4096 = 8,388,608
    unsigned short* u_bf   = xz_bf + 8388608;    // 4,194,304
    unsigned short* dlt_bf = u_bf  + 4194304;    // 4,194,304
    unsigned short* act_bf = dlt_bf + 4194304;   // 2,097,152
    unsigned short* y_bf   = act_bf + 2097152;   // 4,194,304
    unsigned short* dt_bf  = y_bf  + 4194304;    // 131,072

    // one-time conversions (weights both layers + layer-0 act)
    cvt_all<<<(WI8 + WO8 + WX8 + WD8 + AC8 + 255) / 256, 256, 0, stream>>>(
        in_proj_w, out_proj_w, x_proj_w, dt_proj_w, x,
        wi_bf, wo_bf, wx_bf, wd_bf, act_bf);

    for (int layer = 0; layer < NLAYERS; ++layer) {
        const unsigned short* Wi = wi_bf + (size_t)layer * (2 * DINNER) * DMODEL;
        const unsigned short* Wo = wo_bf + (size_t)layer * DMODEL * DINNER;
        const unsigned short* Wx = wx_bf + (size_t)layer * 96 * DINNER;
        const unsigned short* Wd = wd_bf + (size_t)layer * DINNER * DTRANK;
        const float* cw = conv_w    + (size_t)layer * DINNER * DCONV;
        const float* cb = conv_b    + (size_t)layer * DINNER;
        const float* bd = dt_proj_b + (size_t)layer * DINNER;
        const float* Al = A_log     + (size_t)layer * DINNER * DSTATE;
        const float* Dl = Dp        + (size_t)layer * DINNER;

        // 1. xz = act @ W_in^T -> bf16  (TOK x 4096, K=1024)
        {
            dim3 grid(4096 / 128, TOK / 128, 1);
            gemm_bf16<3><<<grid, 256, 0, stream>>>(act_bf, DMODEL, Wi, DMODEL,
                                                   xz_bf, 2 * DINNER, DMODEL,
                                                   2 * DINNER, 0, nullptr);
        }
        // 2. u = silu(conv(xc)+b) -> u_bf
        conv_silu8<<<(TOK * 256) / 256, 256, 0, stream>>>(xz_bf, cw, cb, u_bf);
        // 3. x_dbl partials = u_bf @ Wx^T (TOK x 96, K=2048, split-K16) -> bf16
        {
            dim3 grid(1, TOK / 128, KSX);
            gemm_bf16<5><<<grid, 256, 0, stream>>>(u_bf, DINNER, Wx, DINNER,
                                                   xpart, 96, DINNER / KSX, 96,
                                                   (size_t)TOK * 96, nullptr);
            reduce_x<<<(TOK * 96 + 255) / 256, 256, 0, stream>>>(xpart, xdbl, dt_bf);
        }
        // 4. delta = softplus(dt_bf @ Wd^T + b) -> bf16  (TOK x 2048, K=64)
        {
            dim3 grid(DINNER / 128, TOK / 128, 1);
            gemm_bf16<4><<<grid, 256, 0, stream>>>(dt_bf, DTRANK, Wd, DTRANK,
                                                   dlt_bf, DINNER, DTRANK, DINNER,
                                                   0, bd);
        }
        // 5. chunk-parallel scan -> y_bf
        {
            dim3 gridA(DINNER / 256, BATCH * NCHUNK);
            scan_partial<<<gridA, 256, 0, stream>>>(dlt_bf, u_bf, xdbl, Al,
                                                    hbuf, Pbuf);
            scan_combine<<<(BATCH * DINNER * DSTATE) / 256, 256, 0, stream>>>(hbuf, Pbuf);
            scan_final<<<gridA, 256, 0, stream>>>(dlt_bf, u_bf, xdbl, xz_bf,
                                                  Al, Dl, hbuf, y_bf);
        }
        // 6. out partials = y_bf @ Wo^T (TOK x 1024, K=2048, split-K4) -> reduce
        {
            dim3 grid(DMODEL / 128, TOK / 128, KSO);
            gemm_bf16<3><<<grid, 256, 0, stream>>>(y_bf, DINNER, Wo, DINNER,
                                                   opart, DMODEL, DINNER / KSO,
                                                   DMODEL, (size_t)TOK * DMODEL,
                                                   nullptr);
            const int nred = TOK * DMODEL / 4;
            if (layer == NLAYERS - 1) {
                reduce_out<1><<<(nred + 255) / 256, 256, 0, stream>>>(opart, x, out);
            } else {
                reduce_out<0><<<(nred + 255) / 256, 256, 0, stream>>>(opart, nullptr,
                                                                      act_bf);
            }
        }
    }
}